// Round 5
// baseline (2921.985 us; speedup 1.0000x reference)
//
#include <hip/hip_runtime.h>
#include <hip/hip_bf16.h>

#define BATCH   131072
#define DIM     384
#define KC      256
#define NCB     4
#define ROWS    64
#define THREADS 256
#define RES_LD  388   // padded row stride (floats) for residual tile
#define CB_LD   36    // padded row stride (floats) for codebook chunk
#define DCHUNK  32
#define MARGIN  2e-4f

// numpy pairwise_sum, n=96 block of squares, 8 accumulators (order-preserving).
__device__ __forceinline__ float pw96_sq(const float* a) {
#pragma clang fp contract(off)
    float r0 = a[0]*a[0], r1 = a[1]*a[1], r2 = a[2]*a[2], r3 = a[3]*a[3];
    float r4 = a[4]*a[4], r5 = a[5]*a[5], r6 = a[6]*a[6], r7 = a[7]*a[7];
    for (int i = 8; i < 96; i += 8) {
        r0 += a[i+0]*a[i+0]; r1 += a[i+1]*a[i+1];
        r2 += a[i+2]*a[i+2]; r3 += a[i+3]*a[i+3];
        r4 += a[i+4]*a[i+4]; r5 += a[i+5]*a[i+5];
        r6 += a[i+6]*a[i+6]; r7 += a[i+7]*a[i+7];
    }
    return ((r0+r1)+(r2+r3))+((r4+r5)+(r6+r7));
}

// B_k = numpy pairwise sum of cb_k^2 over 384: ((P0+P1)+(P2+P3))
__global__ __launch_bounds__(256) void ccb_kernel(const float* __restrict__ cb,
                                                  float* __restrict__ bpw) {
    int i = blockIdx.x * 256 + threadIdx.x;
    if (i >= NCB * KC) return;
    const float* row = cb + (size_t)i * DIM;
    {
#pragma clang fp contract(off)
        float P0 = pw96_sq(row), P1 = pw96_sq(row + 96);
        float P2 = pw96_sq(row + 192), P3 = pw96_sq(row + 288);
        bpw[i] = (P0 + P1) + (P2 + P3);
    }
}

__global__ __launch_bounds__(256) void rq_main(const float* __restrict__ x,
                                               const float* __restrict__ cb,
                                               float* __restrict__ out,
                                               const float* __restrict__ bpw,
                                               double* __restrict__ loss_part) {
    __shared__ float  res[ROWS][RES_LD];      // 99328 B
    __shared__ float  cbch[KC][CB_LD];        // 36864 B
    __shared__ float  rowP[ROWS][4];          //  1024 B
    __shared__ float  rowA[ROWS];             //   256 B
    __shared__ float  rowbv[ROWS];            //   256 B
    __shared__ int    rowbk[ROWS];            //   256 B
    __shared__ int    rowcnt[ROWS];           //   256 B
    __shared__ float  lv[ROWS][16];           //  4096 B
    __shared__ int    lk[ROWS][16];           //  4096 B
    __shared__ int    codes_s[ROWS][NCB];     //  1024 B
    __shared__ double red[THREADS];           //  2048 B  => 149504 B total

    const int t  = threadIdx.x;
    const int tr = t >> 4, tc = t & 15;       // group tr owns rows tr*4 .. tr*4+3
    const int row0 = blockIdx.x * ROWS;

    // ---- load x tile into res (coalesced float4); residual_0 = x bit-exact ----
    {
        const float4* x4 = (const float4*)(x + (size_t)row0 * DIM);
        #pragma unroll
        for (int i = 0; i < 24; ++i) {
            int L = i * THREADS + t;
            int r = L / 96, j = L % 96;
            float4 v = x4[(size_t)r * 96 + j];
            *(float4*)&res[r][j * 4] = v;
        }
    }
    __syncthreads();

    double lsum = 0.0;

    for (int s = 0; s < NCB; ++s) {
        const float* cbs = cb + (size_t)s * KC * DIM;

        // ---- rowA = numpy-pairwise sum of res^2 (bit-exact np order) ----
        {
            int r = t >> 2, qi = t & 3;
            rowP[r][qi] = pw96_sq(&res[r][qi * 96]);
        }
        __syncthreads();
        if (t < ROWS) {
#pragma clang fp contract(off)
            rowA[t] = (rowP[t][0] + rowP[t][1]) + (rowP[t][2] + rowP[t][3]);
        }
        // (rowA consumed only after several later barriers)

        // ---- fast f32 screen MAC: acc[rl][j] = <res[tr*4+rl], cb[j*16+tc]> ----
        float acc[4][16];
        #pragma unroll
        for (int a = 0; a < 4; ++a)
            #pragma unroll
            for (int b = 0; b < 16; ++b) acc[a][b] = 0.0f;

        for (int dc = 0; dc < DIM; dc += DCHUNK) {
            __syncthreads();
            {
                const float4* cbs4 = (const float4*)cbs;
                #pragma unroll
                for (int i = 0; i < 8; ++i) {
                    int L = i * THREADS + t;
                    int k = L >> 3, p = L & 7;
                    float4 v = cbs4[(size_t)k * (DIM / 4) + (dc >> 2) + p];
                    *(float4*)&cbch[k][p * 4] = v;
                }
            }
            __syncthreads();
            #pragma unroll
            for (int p = 0; p < 8; ++p) {
                float4 a0 = *(const float4*)&res[tr * 4 + 0][dc + p * 4];
                float4 a1 = *(const float4*)&res[tr * 4 + 1][dc + p * 4];
                float4 a2 = *(const float4*)&res[tr * 4 + 2][dc + p * 4];
                float4 a3 = *(const float4*)&res[tr * 4 + 3][dc + p * 4];
                #pragma unroll
                for (int j = 0; j < 16; ++j) {
                    float4 bb = *(const float4*)&cbch[j * 16 + tc][p * 4];
                    acc[0][j] = fmaf(a0.w, bb.w, fmaf(a0.z, bb.z, fmaf(a0.y, bb.y, fmaf(a0.x, bb.x, acc[0][j]))));
                    acc[1][j] = fmaf(a1.w, bb.w, fmaf(a1.z, bb.z, fmaf(a1.y, bb.y, fmaf(a1.x, bb.x, acc[1][j]))));
                    acc[2][j] = fmaf(a2.w, bb.w, fmaf(a2.z, bb.z, fmaf(a2.y, bb.y, fmaf(a2.x, bb.x, acc[2][j]))));
                    acc[3][j] = fmaf(a3.w, bb.w, fmaf(a3.z, bb.z, fmaf(a3.y, bb.y, fmaf(a3.x, bb.x, acc[3][j]))));
                }
            }
        }

        float ccl[16];
        #pragma unroll
        for (int j = 0; j < 16; ++j) ccl[j] = bpw[s * KC + j * 16 + tc];

        // ---- phase A: per-lane screen best -> LDS; t<64 row min ----
        #pragma unroll
        for (int rl = 0; rl < 4; ++rl) {
            const int r = tr * 4 + rl;
            float bv = 3.4e38f; int bk = 1 << 30;
            #pragma unroll
            for (int j = 0; j < 16; ++j) {
                int k = j * 16 + tc;
                float sval = ccl[j] - 2.0f * acc[rl][j];
                if (sval < bv || (sval == bv && k < bk)) { bv = sval; bk = k; }
            }
            lv[r][tc] = bv; lk[r][tc] = bk;
        }
        __syncthreads();
        if (t < ROWS) {
            float bv = lv[t][0]; int bk = lk[t][0];
            #pragma unroll
            for (int i = 1; i < 16; ++i) {
                float v = lv[t][i]; int k = lk[t][i];
                if (v < bv || (v == bv && k < bk)) { bv = v; bk = k; }
            }
            rowbv[t] = bv; rowbk[t] = bk;
        }
        __syncthreads();

        // ---- phase B: margin candidate masks + counts ----
        unsigned msk[4];
        #pragma unroll
        for (int rl = 0; rl < 4; ++rl) {
            const int r = tr * 4 + rl;
            const float thr = rowbv[r] + MARGIN;
            unsigned m = 0;
            #pragma unroll
            for (int j = 0; j < 16; ++j) {
                float sval = ccl[j] - 2.0f * acc[rl][j];
                if (sval <= thr) m |= (1u << j);
            }
            msk[rl] = m;
            lk[r][tc] = __popc(m);
        }
        __syncthreads();
        if (t < ROWS) {
            int c = 0;
            #pragma unroll
            for (int i = 0; i < 16; ++i) c += lk[t][i];
            rowcnt[t] = c;
            if (c == 1) codes_s[t][s] = rowbk[t] & 0xFF;
        }
        __syncthreads();

        // ---- phase C: exact np-f32 distance for multi-candidate rows ----
        // d = fl( fl(A + B_k) - 2*M_k ), M_k = sequential f32 fma chain (sgemm order)
        #pragma unroll
        for (int rl = 0; rl < 4; ++rl) {
            const int r = tr * 4 + rl;
            if (rowcnt[r] >= 2) {
                float bd = 3.4e38f; int bk = 1 << 30;
                unsigned m = msk[rl];
                while (m) {
                    int j = __ffs(m) - 1; m &= m - 1;
                    int k = j * 16 + tc;
                    const float* crow = cbs + (size_t)k * DIM;
                    float acc32 = 0.0f;
                    for (int d = 0; d < DIM; ++d)
                        acc32 = fmaf(res[r][d], crow[d], acc32);
                    float T  = rowA[r] + ccl[j];     // fl(A + B_k)
                    float dv = T - 2.0f * acc32;     // fl(T - 2M), 2M exact
                    if (dv < bd || (dv == bd && k < bk)) { bd = dv; bk = k; }
                }
                lv[r][tc] = bd; lk[r][tc] = bk;
            }
        }
        __syncthreads();
        if (t < ROWS && rowcnt[t] >= 2) {
            float bv = lv[t][0]; int bk = lk[t][0];
            #pragma unroll
            for (int i = 1; i < 16; ++i) {
                float v = lv[t][i]; int k = lk[t][i];
                if (v < bv || (v == bv && k < bk)) { bv = v; bk = k; }
            }
            codes_s[t][s] = bk & 0xFF;
        }
        __syncthreads();

        // ---- residual/rec chain (bit-exact np elementwise), loss, outputs ----
        {
            const float4* x4 = (const float4*)(x + (size_t)row0 * DIM);
            #pragma unroll
            for (int i = 0; i < 24; ++i) {
                int L = i * THREADS + t;
                int r = L / 96, c4 = L % 96;
                float4 xv = (s == 0) ? *(const float4*)&res[r][c4 * 4] : x4[L];
                float4 rec = make_float4(0.f, 0.f, 0.f, 0.f);
                float4 df  = make_float4(0.f, 0.f, 0.f, 0.f);
                for (int j = 0; j <= s; ++j) {
                    int code = codes_s[r][j] & 0xFF;
                    float4 q = ((const float4*)(cb + ((size_t)j * KC + code) * DIM))[c4];
                    float4 rv;                        // fl(x - rec); j=0: x-0 = x exact
                    rv.x = xv.x - rec.x; rv.y = xv.y - rec.y;
                    rv.z = xv.z - rec.z; rv.w = xv.w - rec.w;
                    df.x = q.x - rv.x; df.y = q.y - rv.y;
                    df.z = q.z - rv.z; df.w = q.w - rv.w;
                    float4 qst;                       // fl(r + fl(q - r))
                    qst.x = rv.x + df.x; qst.y = rv.y + df.y;
                    qst.z = rv.z + df.z; qst.w = rv.w + df.w;
                    rec.x = rec.x + qst.x; rec.y = rec.y + qst.y;
                    rec.z = rec.z + qst.z; rec.w = rec.w + qst.w;
                }
                // loss for stage s uses diff at j==s (f32 values, f64 accumulate)
                lsum = fma((double)df.x, (double)df.x, lsum);
                lsum = fma((double)df.y, (double)df.y, lsum);
                lsum = fma((double)df.z, (double)df.z, lsum);
                lsum = fma((double)df.w, (double)df.w, lsum);
                if (s < NCB - 1) {
                    float4 rn;                        // residual = fl(x - rec)
                    rn.x = xv.x - rec.x; rn.y = xv.y - rec.y;
                    rn.z = xv.z - rec.z; rn.w = xv.w - rec.w;
                    *(float4*)&res[r][c4 * 4] = rn;
                } else {
                    ((float4*)out)[(size_t)blockIdx.x * (ROWS * 96) + L] = rec;
                }
            }
        }
        __syncthreads();
    }

    // ---- codes as f32 values into out[B*D .. B*D + B*4) ----
    if (t < ROWS) {
        float4 c;
        c.x = (float)(codes_s[t][0] & 0xFF);
        c.y = (float)(codes_s[t][1] & 0xFF);
        c.z = (float)(codes_s[t][2] & 0xFF);
        c.w = (float)(codes_s[t][3] & 0xFF);
        *(float4*)&out[(size_t)BATCH * DIM + (size_t)(row0 + t) * NCB] = c;
    }

    // ---- per-block loss partial ----
    red[t] = lsum;
    __syncthreads();
    for (int st = 128; st > 0; st >>= 1) {
        if (t < st) red[t] += red[t + st];
        __syncthreads();
    }
    if (t == 0) loss_part[blockIdx.x] = red[0];
}

__global__ __launch_bounds__(256) void loss_fin(const double* __restrict__ loss_part,
                                                float* __restrict__ out) {
    __shared__ double red[256];
    int t = threadIdx.x;
    double s = 0.0;
    for (int i = t; i < BATCH / ROWS; i += 256) s += loss_part[i];
    red[t] = s;
    __syncthreads();
    for (int st = 128; st > 0; st >>= 1) {
        if (t < st) red[t] += red[t + st];
        __syncthreads();
    }
    if (t == 0) {
        double total = red[0] * (2.0 / ((double)BATCH * (double)DIM));
        out[(size_t)BATCH * DIM + (size_t)BATCH * NCB] = (float)total;
    }
}

extern "C" void kernel_launch(void* const* d_in, const int* in_sizes, int n_in,
                              void* d_out, int out_size, void* d_ws, size_t ws_size,
                              hipStream_t stream) {
    const float* x  = (const float*)d_in[0];
    const float* cb = (const float*)d_in[1];
    float* out = (float*)d_out;

    double* loss_part = (double*)d_ws;                     // 2048 * 8 = 16 KB
    float*  bpw       = (float*)((char*)d_ws + 16384);     // 1024 * 4 = 4 KB

    ccb_kernel<<<dim3(4), dim3(256), 0, stream>>>(cb, bpw);
    rq_main<<<dim3(BATCH / ROWS), dim3(THREADS), 0, stream>>>(x, cb, out, bpw, loss_part);
    loss_fin<<<dim3(1), dim3(256), 0, stream>>>(loss_part, out);
}

// Round 6
// 1916.639 us; speedup vs baseline: 1.5245x; 1.5245x over previous
//
#include <hip/hip_runtime.h>
#include <hip/hip_bf16.h>

#define BATCH   131072
#define DIM     384
#define KC      256
#define NCB     4
#define ROWS    64
#define THREADS 256
#define RES_LD  388   // padded row stride (floats) for residual tile
#define NKT     12    // k-tiles of 32 (384 = 12*32)
#define CBLD    40    // bf16 stride for staged B rows (80B: 2-way banks, 16B aligned)
#define MARGIN  2.5e-4f

typedef __attribute__((ext_vector_type(8))) short bf16x8;
typedef __attribute__((ext_vector_type(4))) float f32x4;

// numpy pairwise_sum, n=96 block of squares, 8 accumulators (order-preserving).
__device__ __forceinline__ float pw96_sq(const float* a) {
#pragma clang fp contract(off)
    float r0 = a[0]*a[0], r1 = a[1]*a[1], r2 = a[2]*a[2], r3 = a[3]*a[3];
    float r4 = a[4]*a[4], r5 = a[5]*a[5], r6 = a[6]*a[6], r7 = a[7]*a[7];
    for (int i = 8; i < 96; i += 8) {
        r0 += a[i+0]*a[i+0]; r1 += a[i+1]*a[i+1];
        r2 += a[i+2]*a[i+2]; r3 += a[i+3]*a[i+3];
        r4 += a[i+4]*a[i+4]; r5 += a[i+5]*a[i+5];
        r6 += a[i+6]*a[i+6]; r7 += a[i+7]*a[i+7];
    }
    return ((r0+r1)+(r2+r3))+((r4+r5)+(r6+r7));
}

// B_k = numpy pairwise sum of cb_k^2 over 384: ((P0+P1)+(P2+P3))
__global__ __launch_bounds__(256) void ccb_kernel(const float* __restrict__ cb,
                                                  float* __restrict__ bpw) {
    int i = blockIdx.x * 256 + threadIdx.x;
    if (i >= NCB * KC) return;
    const float* row = cb + (size_t)i * DIM;
    {
#pragma clang fp contract(off)
        float P0 = pw96_sq(row), P1 = pw96_sq(row + 96);
        float P2 = pw96_sq(row + 192), P3 = pw96_sq(row + 288);
        bpw[i] = (P0 + P1) + (P2 + P3);
    }
}

// Split codebook into k-tile-major bf16 hi/lo: out[((s*NKT+kt)*KC+cand)*32 + k]
__global__ __launch_bounds__(256) void split_kernel(const float* __restrict__ cb,
                                                    short* __restrict__ hi,
                                                    short* __restrict__ lo) {
    int idx = blockIdx.x * 256 + threadIdx.x;   // over 4*12*256*32 = 393216 elems
    if (idx >= NCB * NKT * KC * 32) return;
    int k    = idx & 31;
    int cand = (idx >> 5) & 255;
    int kt   = (idx >> 13) % NKT;
    int s    = idx / (NKT * KC * 32);
    float v = cb[((size_t)(s * KC + cand)) * DIM + kt * 32 + k];
    __hip_bfloat16 h = __float2bfloat16(v);
    float hv = __bfloat162float(h);
    __hip_bfloat16 l = __float2bfloat16(v - hv);
    hi[idx] = *reinterpret_cast<short*>(&h);
    lo[idx] = *reinterpret_cast<short*>(&l);
}

__device__ __forceinline__ void cvt8(const float* p, bf16x8& hi, bf16x8& lo) {
    #pragma unroll
    for (int i = 0; i < 8; ++i) {
        float v = p[i];
        __hip_bfloat16 h = __float2bfloat16(v);
        float hv = __bfloat162float(h);
        __hip_bfloat16 l = __float2bfloat16(v - hv);
        hi[i] = *reinterpret_cast<short*>(&h);
        lo[i] = *reinterpret_cast<short*>(&l);
    }
}

__global__ __launch_bounds__(256) void rq_main(const float* __restrict__ x,
                                               const float* __restrict__ cb,
                                               float* __restrict__ out,
                                               const float* __restrict__ bpw,
                                               const short* __restrict__ cbh_g,
                                               const short* __restrict__ cbl_g,
                                               double* __restrict__ loss_part) {
    __shared__ float  res[ROWS][RES_LD];      // 99328 B
    __shared__ short  cbh[KC][CBLD];          // 20480 B
    __shared__ short  cbl[KC][CBLD];          // 20480 B
    __shared__ float  rowP[ROWS][4];          //  1024 B
    __shared__ float  rowA[ROWS];             //   256 B
    __shared__ float  lvA[ROWS][4];           //  1024 B
    __shared__ int    lkA[ROWS][4];           //  1024 B
    __shared__ int    cntA[ROWS][4];          //  1024 B
    __shared__ int    codes_s[ROWS][NCB];     //  1024 B
    __shared__ double red[THREADS];           //  2048 B   => 147712 B

    const int t  = threadIdx.x;
    const int w  = t >> 6;        // wave 0..3 (owns cand-tiles 4w..4w+3)
    const int l  = t & 63;
    const int lg = l >> 4;        // k-group 0..3
    const int li = l & 15;
    const int row0 = blockIdx.x * ROWS;

    // ---- load x tile into res (coalesced float4); residual_0 = x bit-exact ----
    {
        const float4* x4 = (const float4*)(x + (size_t)row0 * DIM);
        #pragma unroll
        for (int i = 0; i < 24; ++i) {
            int L = i * THREADS + t;
            int r = L / 96, j = L % 96;
            float4 v = x4[(size_t)r * 96 + j];
            *(float4*)&res[r][j * 4] = v;
        }
    }
    __syncthreads();

    double lsum = 0.0;

    for (int s = 0; s < NCB; ++s) {
        const float* cbs = cb + (size_t)s * KC * DIM;

        // ---- rowA = numpy-pairwise sum of res^2 (bit-exact np order) ----
        {
            int r = t >> 2, qi = t & 3;
            rowP[r][qi] = pw96_sq(&res[r][qi * 96]);
        }
        __syncthreads();
        if (t < ROWS) {
#pragma clang fp contract(off)
            rowA[t] = (rowP[t][0] + rowP[t][1]) + (rowP[t][2] + rowP[t][3]);
        }
        // rowA consumed in refine (several barriers later)

        // ---- MFMA screen: acc[rt][jc] covers rows rt*16.. x cands (4w+jc)*16.. ----
        f32x4 acc[4][4];
        #pragma unroll
        for (int a = 0; a < 4; ++a)
            #pragma unroll
            for (int b = 0; b < 4; ++b) acc[a][b] = (f32x4){0.f, 0.f, 0.f, 0.f};

        for (int kt = 0; kt < NKT; ++kt) {
            __syncthreads();   // protect cbh/cbl reuse (and rowA write on kt==0)
            {   // stage B chunk: thread t = cand t, 32 k's of hi and lo (coalesced 64B)
                size_t base = ((size_t)(s * NKT + kt) * KC + t) * 32;
                const int4* gh = (const int4*)(cbh_g + base);
                const int4* gl = (const int4*)(cbl_g + base);
                int4 h0 = gh[0], h1 = gh[1], h2 = gh[2], h3 = gh[3];
                int4 l0 = gl[0], l1 = gl[1], l2 = gl[2], l3 = gl[3];
                *(int4*)&cbh[t][0]  = h0; *(int4*)&cbh[t][8]  = h1;
                *(int4*)&cbh[t][16] = h2; *(int4*)&cbh[t][24] = h3;
                *(int4*)&cbl[t][0]  = l0; *(int4*)&cbl[t][8]  = l1;
                *(int4*)&cbl[t][16] = l2; *(int4*)&cbl[t][24] = l3;
            }
            __syncthreads();

            // B fragments: cand = w*64 + jc*16 + li, k = kt*32 + lg*8 + i
            bf16x8 bh[4], bl[4];
            #pragma unroll
            for (int jc = 0; jc < 4; ++jc) {
                bh[jc] = *(const bf16x8*)&cbh[w * 64 + jc * 16 + li][lg * 8];
                bl[jc] = *(const bf16x8*)&cbl[w * 64 + jc * 16 + li][lg * 8];
            }
            // A fragments per row-tile: row = rt*16 + li, k = kt*32 + lg*8 + i
            #pragma unroll
            for (int rt = 0; rt < 4; ++rt) {
                bf16x8 ah, al;
                cvt8(&res[rt * 16 + li][kt * 32 + lg * 8], ah, al);
                #pragma unroll
                for (int jc = 0; jc < 4; ++jc) {
                    acc[rt][jc] = __builtin_amdgcn_mfma_f32_16x16x32_bf16(ah, bh[jc], acc[rt][jc], 0, 0, 0);
                    acc[rt][jc] = __builtin_amdgcn_mfma_f32_16x16x32_bf16(ah, bl[jc], acc[rt][jc], 0, 0, 0);
                    acc[rt][jc] = __builtin_amdgcn_mfma_f32_16x16x32_bf16(al, bh[jc], acc[rt][jc], 0, 0, 0);
                }
            }
        }

        // C/D frag: acc[rt][jc][q] = dot(row = rt*16 + lg*4 + q, cand = (4w+jc)*16 + li)
        float ccl4[4];
        #pragma unroll
        for (int jc = 0; jc < 4; ++jc) ccl4[jc] = bpw[s * KC + w * 64 + jc * 16 + li];

        // ---- phase A: per-lane best over jc; butterfly over li; cross-wave via LDS ----
        float pbv[4][4]; int pbk[4][4];
        #pragma unroll
        for (int rt = 0; rt < 4; ++rt)
            #pragma unroll
            for (int q = 0; q < 4; ++q) {
                float bv = 3.4e38f; int bk = 1 << 30;
                #pragma unroll
                for (int jc = 0; jc < 4; ++jc) {
                    float sv = ccl4[jc] - 2.0f * acc[rt][jc][q];
                    int k = w * 64 + jc * 16 + li;
                    if (sv < bv || (sv == bv && k < bk)) { bv = sv; bk = k; }
                }
                pbv[rt][q] = bv; pbk[rt][q] = bk;
            }
        #pragma unroll
        for (int m = 1; m < 16; m <<= 1) {
            #pragma unroll
            for (int rt = 0; rt < 4; ++rt)
                #pragma unroll
                for (int q = 0; q < 4; ++q) {
                    float ov = __shfl_xor(pbv[rt][q], m);
                    int   ok = __shfl_xor(pbk[rt][q], m);
                    if (ov < pbv[rt][q] || (ov == pbv[rt][q] && ok < pbk[rt][q])) {
                        pbv[rt][q] = ov; pbk[rt][q] = ok;
                    }
                }
        }
        #pragma unroll
        for (int rt = 0; rt < 4; ++rt)
            #pragma unroll
            for (int q = 0; q < 4; ++q)
                if (li == rt * 4 + q) {
                    lvA[rt * 16 + lg * 4 + q][w] = pbv[rt][q];
                    lkA[rt * 16 + lg * 4 + q][w] = pbk[rt][q];
                }
        __syncthreads();

        // ---- phase A2+B: combine across waves; margin counts ----
        float rbv[4][4]; int rbk[4][4]; int rcnt[4][4];
        #pragma unroll
        for (int rt = 0; rt < 4; ++rt)
            #pragma unroll
            for (int q = 0; q < 4; ++q) {
                int row = rt * 16 + lg * 4 + q;
                float bv = lvA[row][0]; int bk = lkA[row][0];
                #pragma unroll
                for (int ww = 1; ww < 4; ++ww) {
                    float v = lvA[row][ww]; int k = lkA[row][ww];
                    if (v < bv || (v == bv && k < bk)) { bv = v; bk = k; }
                }
                rbv[rt][q] = bv; rbk[rt][q] = bk;
                int c = 0;
                #pragma unroll
                for (int jc = 0; jc < 4; ++jc) {
                    float sv = ccl4[jc] - 2.0f * acc[rt][jc][q];
                    c += (sv <= bv + MARGIN) ? 1 : 0;
                }
                rcnt[rt][q] = c;
            }
        #pragma unroll
        for (int m = 1; m < 16; m <<= 1) {
            #pragma unroll
            for (int rt = 0; rt < 4; ++rt)
                #pragma unroll
                for (int q = 0; q < 4; ++q)
                    rcnt[rt][q] += __shfl_xor(rcnt[rt][q], m);
        }
        #pragma unroll
        for (int rt = 0; rt < 4; ++rt)
            #pragma unroll
            for (int q = 0; q < 4; ++q)
                if (li == rt * 4 + q) cntA[rt * 16 + lg * 4 + q][w] = rcnt[rt][q];
        __syncthreads();
        #pragma unroll
        for (int rt = 0; rt < 4; ++rt)
            #pragma unroll
            for (int q = 0; q < 4; ++q) {
                int row = rt * 16 + lg * 4 + q;
                rcnt[rt][q] = cntA[row][0] + cntA[row][1] + cntA[row][2] + cntA[row][3];
                if (w == 0 && li == rt * 4 + q && rcnt[rt][q] == 1)
                    codes_s[row][s] = rbk[rt][q] & 0xFF;
            }

        // ---- phase C: exact np-f32 refine for rows with >=2 margin candidates ----
        #pragma unroll
        for (int rt = 0; rt < 4; ++rt)
            #pragma unroll
            for (int q = 0; q < 4; ++q) {
                float bd = 3.4e38f; int bk = 1 << 30;
                if (rcnt[rt][q] >= 2) {
                    int row = rt * 16 + lg * 4 + q;
                    const float thr = rbv[rt][q] + MARGIN;
                    const float* rrow = &res[row][0];
                    #pragma unroll
                    for (int jc = 0; jc < 4; ++jc) {
                        float sv = ccl4[jc] - 2.0f * acc[rt][jc][q];
                        if (sv <= thr) {
                            int k = w * 64 + jc * 16 + li;
                            const float* crow = cbs + (size_t)k * DIM;
                            float a32 = 0.0f;
                            for (int d = 0; d < DIM; ++d)
                                a32 = fmaf(rrow[d], crow[d], a32);
                            float T  = rowA[row] + ccl4[jc];   // fl(A + B_k)
                            float dv = T - 2.0f * a32;         // fl(T - 2M), 2M exact
                            if (dv < bd || (dv == bd && k < bk)) { bd = dv; bk = k; }
                        }
                    }
                }
                pbv[rt][q] = bd; pbk[rt][q] = bk;
            }
        #pragma unroll
        for (int m = 1; m < 16; m <<= 1) {
            #pragma unroll
            for (int rt = 0; rt < 4; ++rt)
                #pragma unroll
                for (int q = 0; q < 4; ++q) {
                    float ov = __shfl_xor(pbv[rt][q], m);
                    int   ok = __shfl_xor(pbk[rt][q], m);
                    if (ov < pbv[rt][q] || (ov == pbv[rt][q] && ok < pbk[rt][q])) {
                        pbv[rt][q] = ov; pbk[rt][q] = ok;
                    }
                }
        }
        #pragma unroll
        for (int rt = 0; rt < 4; ++rt)
            #pragma unroll
            for (int q = 0; q < 4; ++q)
                if (li == rt * 4 + q) {
                    lvA[rt * 16 + lg * 4 + q][w] = pbv[rt][q];
                    lkA[rt * 16 + lg * 4 + q][w] = pbk[rt][q];
                }
        __syncthreads();
        #pragma unroll
        for (int rt = 0; rt < 4; ++rt)
            #pragma unroll
            for (int q = 0; q < 4; ++q)
                if (w == 0 && li == rt * 4 + q && rcnt[rt][q] >= 2) {
                    int row = rt * 16 + lg * 4 + q;
                    float bv = lvA[row][0]; int bk = lkA[row][0];
                    #pragma unroll
                    for (int ww = 1; ww < 4; ++ww) {
                        float v = lvA[row][ww]; int k = lkA[row][ww];
                        if (v < bv || (v == bv && k < bk)) { bv = v; bk = k; }
                    }
                    codes_s[row][s] = bk & 0xFF;
                }
        __syncthreads();

        // ---- residual/rec chain (bit-exact np elementwise), loss, outputs ----
        {
            const float4* x4 = (const float4*)(x + (size_t)row0 * DIM);
            #pragma unroll
            for (int i = 0; i < 24; ++i) {
                int L = i * THREADS + t;
                int r = L / 96, c4 = L % 96;
                float4 xv = (s == 0) ? *(const float4*)&res[r][c4 * 4] : x4[L];
                float4 rec = make_float4(0.f, 0.f, 0.f, 0.f);
                float4 df  = make_float4(0.f, 0.f, 0.f, 0.f);
                for (int j = 0; j <= s; ++j) {
                    int code = codes_s[r][j] & 0xFF;
                    float4 q = ((const float4*)(cb + ((size_t)j * KC + code) * DIM))[c4];
                    float4 rv;                        // fl(x - rec); j=0: x-0 = x exact
                    rv.x = xv.x - rec.x; rv.y = xv.y - rec.y;
                    rv.z = xv.z - rec.z; rv.w = xv.w - rec.w;
                    df.x = q.x - rv.x; df.y = q.y - rv.y;
                    df.z = q.z - rv.z; df.w = q.w - rv.w;
                    float4 qst;                       // fl(r + fl(q - r))
                    qst.x = rv.x + df.x; qst.y = rv.y + df.y;
                    qst.z = rv.z + df.z; qst.w = rv.w + df.w;
                    rec.x = rec.x + qst.x; rec.y = rec.y + qst.y;
                    rec.z = rec.z + qst.z; rec.w = rec.w + qst.w;
                }
                lsum = fma((double)df.x, (double)df.x, lsum);
                lsum = fma((double)df.y, (double)df.y, lsum);
                lsum = fma((double)df.z, (double)df.z, lsum);
                lsum = fma((double)df.w, (double)df.w, lsum);
                if (s < NCB - 1) {
                    float4 rn;                        // residual = fl(x - rec)
                    rn.x = xv.x - rec.x; rn.y = xv.y - rec.y;
                    rn.z = xv.z - rec.z; rn.w = xv.w - rec.w;
                    *(float4*)&res[r][c4 * 4] = rn;
                } else {
                    ((float4*)out)[(size_t)blockIdx.x * (ROWS * 96) + L] = rec;
                }
            }
        }
        __syncthreads();
    }

    // ---- codes as f32 values into out[B*D .. B*D + B*4) ----
    if (t < ROWS) {
        float4 c;
        c.x = (float)(codes_s[t][0] & 0xFF);
        c.y = (float)(codes_s[t][1] & 0xFF);
        c.z = (float)(codes_s[t][2] & 0xFF);
        c.w = (float)(codes_s[t][3] & 0xFF);
        *(float4*)&out[(size_t)BATCH * DIM + (size_t)(row0 + t) * NCB] = c;
    }

    // ---- per-block loss partial ----
    red[t] = lsum;
    __syncthreads();
    for (int st = 128; st > 0; st >>= 1) {
        if (t < st) red[t] += red[t + st];
        __syncthreads();
    }
    if (t == 0) loss_part[blockIdx.x] = red[0];
}

__global__ __launch_bounds__(256) void loss_fin(const double* __restrict__ loss_part,
                                                float* __restrict__ out) {
    __shared__ double red[256];
    int t = threadIdx.x;
    double s = 0.0;
    for (int i = t; i < BATCH / ROWS; i += 256) s += loss_part[i];
    red[t] = s;
    __syncthreads();
    for (int st = 128; st > 0; st >>= 1) {
        if (t < st) red[t] += red[t + st];
        __syncthreads();
    }
    if (t == 0) {
        double total = red[0] * (2.0 / ((double)BATCH * (double)DIM));
        out[(size_t)BATCH * DIM + (size_t)BATCH * NCB] = (float)total;
    }
}

extern "C" void kernel_launch(void* const* d_in, const int* in_sizes, int n_in,
                              void* d_out, int out_size, void* d_ws, size_t ws_size,
                              hipStream_t stream) {
    const float* x  = (const float*)d_in[0];
    const float* cb = (const float*)d_in[1];
    float* out = (float*)d_out;

    double* loss_part = (double*)d_ws;                        // 16 KB @ 0
    float*  bpw       = (float*)((char*)d_ws + 16384);        //  4 KB
    short*  cbh_g     = (short*)((char*)d_ws + 32768);        // 768 KB
    short*  cbl_g     = (short*)((char*)d_ws + 32768 + 786432);

    ccb_kernel<<<dim3(4), dim3(256), 0, stream>>>(cb, bpw);
    split_kernel<<<dim3((NCB * NKT * KC * 32 + 255) / 256), dim3(256), 0, stream>>>(cb, cbh_g, cbl_g);
    rq_main<<<dim3(BATCH / ROWS), dim3(THREADS), 0, stream>>>(x, cb, out, bpw,
                                                              cbh_g, cbl_g, loss_part);
    loss_fin<<<dim3(1), dim3(256), 0, stream>>>(loss_part, out);
}

// Round 7
// 1743.461 us; speedup vs baseline: 1.6760x; 1.0993x over previous
//
#include <hip/hip_runtime.h>
#include <hip/hip_bf16.h>

#define BATCH   131072
#define DIM     384
#define KC      256
#define NCB     4
#define ROWS    64
#define THREADS 512
#define RES_LD  388   // padded row stride (floats) for residual tile
#define NKT     12    // k-tiles of 32 (384 = 12*32)
#define CBLD    40    // bf16 stride for staged B rows (80B: 2-way banks, 16B aligned)
#define NW      8     // waves per block
#define MARGIN  2.5e-4f

typedef __attribute__((ext_vector_type(8))) short bf16x8;
typedef __attribute__((ext_vector_type(4))) float f32x4;

// numpy pairwise_sum, n=96 block of squares, 8 accumulators (order-preserving).
__device__ __forceinline__ float pw96_sq(const float* a) {
#pragma clang fp contract(off)
    float r0 = a[0]*a[0], r1 = a[1]*a[1], r2 = a[2]*a[2], r3 = a[3]*a[3];
    float r4 = a[4]*a[4], r5 = a[5]*a[5], r6 = a[6]*a[6], r7 = a[7]*a[7];
    for (int i = 8; i < 96; i += 8) {
        r0 += a[i+0]*a[i+0]; r1 += a[i+1]*a[i+1];
        r2 += a[i+2]*a[i+2]; r3 += a[i+3]*a[i+3];
        r4 += a[i+4]*a[i+4]; r5 += a[i+5]*a[i+5];
        r6 += a[i+6]*a[i+6]; r7 += a[i+7]*a[i+7];
    }
    return ((r0+r1)+(r2+r3))+((r4+r5)+(r6+r7));
}

// B_k = numpy pairwise sum of cb_k^2 over 384: ((P0+P1)+(P2+P3))
__global__ __launch_bounds__(256) void ccb_kernel(const float* __restrict__ cb,
                                                  float* __restrict__ bpw) {
    int i = blockIdx.x * 256 + threadIdx.x;
    if (i >= NCB * KC) return;
    const float* row = cb + (size_t)i * DIM;
    {
#pragma clang fp contract(off)
        float P0 = pw96_sq(row), P1 = pw96_sq(row + 96);
        float P2 = pw96_sq(row + 192), P3 = pw96_sq(row + 288);
        bpw[i] = (P0 + P1) + (P2 + P3);
    }
}

// Split codebook into k-tile-major bf16 hi/lo: out[((s*NKT+kt)*KC+cand)*32 + k]
__global__ __launch_bounds__(256) void split_kernel(const float* __restrict__ cb,
                                                    short* __restrict__ hi,
                                                    short* __restrict__ lo) {
    int idx = blockIdx.x * 256 + threadIdx.x;   // over 4*12*256*32 = 393216 elems
    if (idx >= NCB * NKT * KC * 32) return;
    int k    = idx & 31;
    int cand = (idx >> 5) & 255;
    int kt   = (idx >> 13) % NKT;
    int s    = idx / (NKT * KC * 32);
    float v = cb[((size_t)(s * KC + cand)) * DIM + kt * 32 + k];
    __hip_bfloat16 h = __float2bfloat16(v);
    float hv = __bfloat162float(h);
    __hip_bfloat16 l = __float2bfloat16(v - hv);
    hi[idx] = *reinterpret_cast<short*>(&h);
    lo[idx] = *reinterpret_cast<short*>(&l);
}

__device__ __forceinline__ void cvt8(const float* p, bf16x8& hi, bf16x8& lo) {
    #pragma unroll
    for (int i = 0; i < 8; ++i) {
        float v = p[i];
        __hip_bfloat16 h = __float2bfloat16(v);
        float hv = __bfloat162float(h);
        __hip_bfloat16 l = __float2bfloat16(v - hv);
        hi[i] = *reinterpret_cast<short*>(&h);
        lo[i] = *reinterpret_cast<short*>(&l);
    }
}

__global__ __launch_bounds__(512, 2) void rq_main(const float* __restrict__ x,
                                                  const float* __restrict__ cb,
                                                  float* __restrict__ out,
                                                  const float* __restrict__ bpw,
                                                  const short* __restrict__ cbh_g,
                                                  const short* __restrict__ cbl_g,
                                                  double* __restrict__ loss_part) {
    __shared__ float  res[ROWS][RES_LD];      // 99328 B
    __shared__ short  cbh[KC][CBLD];          // 20480 B
    __shared__ short  cbl[KC][CBLD];          // 20480 B
    __shared__ float  rowP[ROWS][4];          //  1024 B
    __shared__ float  rowA[ROWS];             //   256 B
    __shared__ float  lvA[ROWS][NW];          //  2048 B
    __shared__ int    lkA[ROWS][NW];          //  2048 B
    __shared__ int    cntA[ROWS][NW];         //  2048 B
    __shared__ int    codes_s[ROWS][NCB];     //  1024 B
    __shared__ double red[THREADS];           //  4096 B   => 152832 B

    const int t  = threadIdx.x;
    const int w  = t >> 6;        // wave 0..7 (owns cand-tiles 2w, 2w+1)
    const int l  = t & 63;
    const int lg = l >> 4;        // k-group 0..3
    const int li = l & 15;
    const int row0 = blockIdx.x * ROWS;
    const float4* x4 = (const float4*)(x + (size_t)row0 * DIM);

    float4 rec[12];               // running reconstruction, this thread's 12 float4s
    #pragma unroll
    for (int i = 0; i < 12; ++i) rec[i] = make_float4(0.f, 0.f, 0.f, 0.f);

    double lsum = 0.0;

    for (int s = 0; s < NCB; ++s) {
        const float* cbs = cb + (size_t)s * KC * DIM;

        // ---- res_s = fl(x - rec) (bit-exact np; s=0: x-0 = x), write to LDS ----
        __syncthreads();          // prior stage's res readers (refine+chain) done
        #pragma unroll
        for (int i = 0; i < 12; ++i) {
            int L = i * THREADS + t;
            int r = L / 96, c4 = L % 96;
            float4 xv = x4[L];
            float4 rs;
            rs.x = xv.x - rec[i].x; rs.y = xv.y - rec[i].y;
            rs.z = xv.z - rec[i].z; rs.w = xv.w - rec[i].w;
            *(float4*)&res[r][c4 * 4] = rs;
        }
        __syncthreads();

        // ---- rowA = numpy-pairwise sum of res^2 (bit-exact np order) ----
        if (t < 256) {
            int r = t >> 2, qi = t & 3;
            rowP[r][qi] = pw96_sq(&res[r][qi * 96]);
        }
        __syncthreads();
        if (t < ROWS) {
#pragma clang fp contract(off)
            rowA[t] = (rowP[t][0] + rowP[t][1]) + (rowP[t][2] + rowP[t][3]);
        }
        // rowA consumed in refine (several barriers later; kt==0 barrier covers it)

        // ---- MFMA screen: acc[rt][jc] = rows rt*16.. x cands (2w+jc)*16.. ----
        f32x4 acc[4][2];
        #pragma unroll
        for (int a = 0; a < 4; ++a)
            #pragma unroll
            for (int b = 0; b < 2; ++b) acc[a][b] = (f32x4){0.f, 0.f, 0.f, 0.f};

        for (int kt = 0; kt < NKT; ++kt) {
            __syncthreads();   // protect cbh/cbl reuse (and rowA write on kt==0)
            {   // stage B chunk: thread pair stages cand c = t>>1, half h = t&1
                int c = t >> 1, h = t & 1;
                size_t base = ((size_t)(s * NKT + kt) * KC + c) * 32 + h * 16;
                const int4* gh = (const int4*)(cbh_g + base);
                const int4* gl = (const int4*)(cbl_g + base);
                int4 h0 = gh[0], h1 = gh[1];
                int4 l0 = gl[0], l1 = gl[1];
                *(int4*)&cbh[c][h * 16]     = h0;
                *(int4*)&cbh[c][h * 16 + 8] = h1;
                *(int4*)&cbl[c][h * 16]     = l0;
                *(int4*)&cbl[c][h * 16 + 8] = l1;
            }
            __syncthreads();

            // B fragments: cand = w*32 + jc*16 + li, k = kt*32 + lg*8 + i
            bf16x8 bh[2], bl[2];
            #pragma unroll
            for (int jc = 0; jc < 2; ++jc) {
                bh[jc] = *(const bf16x8*)&cbh[w * 32 + jc * 16 + li][lg * 8];
                bl[jc] = *(const bf16x8*)&cbl[w * 32 + jc * 16 + li][lg * 8];
            }
            // A fragments per row-tile: row = rt*16 + li, k = kt*32 + lg*8 + i
            #pragma unroll
            for (int rt = 0; rt < 4; ++rt) {
                bf16x8 ah, al;
                cvt8(&res[rt * 16 + li][kt * 32 + lg * 8], ah, al);
                #pragma unroll
                for (int jc = 0; jc < 2; ++jc) {
                    acc[rt][jc] = __builtin_amdgcn_mfma_f32_16x16x32_bf16(ah, bh[jc], acc[rt][jc], 0, 0, 0);
                    acc[rt][jc] = __builtin_amdgcn_mfma_f32_16x16x32_bf16(ah, bl[jc], acc[rt][jc], 0, 0, 0);
                    acc[rt][jc] = __builtin_amdgcn_mfma_f32_16x16x32_bf16(al, bh[jc], acc[rt][jc], 0, 0, 0);
                }
            }
        }

        // C/D frag: acc[rt][jc][q] = dot(row = rt*16 + lg*4 + q, cand = (2w+jc)*16 + li)
        float ccl2[2];
        #pragma unroll
        for (int jc = 0; jc < 2; ++jc) ccl2[jc] = bpw[s * KC + w * 32 + jc * 16 + li];

        // ---- phase A: per-lane best over jc; butterfly over li; to LDS per wave ----
        float pbv[4][4]; int pbk[4][4];
        #pragma unroll
        for (int rt = 0; rt < 4; ++rt)
            #pragma unroll
            for (int q = 0; q < 4; ++q) {
                float bv = 3.4e38f; int bk = 1 << 30;
                #pragma unroll
                for (int jc = 0; jc < 2; ++jc) {
                    float sv = ccl2[jc] - 2.0f * acc[rt][jc][q];
                    int k = w * 32 + jc * 16 + li;
                    if (sv < bv || (sv == bv && k < bk)) { bv = sv; bk = k; }
                }
                pbv[rt][q] = bv; pbk[rt][q] = bk;
            }
        #pragma unroll
        for (int m = 1; m < 16; m <<= 1) {
            #pragma unroll
            for (int rt = 0; rt < 4; ++rt)
                #pragma unroll
                for (int q = 0; q < 4; ++q) {
                    float ov = __shfl_xor(pbv[rt][q], m);
                    int   ok = __shfl_xor(pbk[rt][q], m);
                    if (ov < pbv[rt][q] || (ov == pbv[rt][q] && ok < pbk[rt][q])) {
                        pbv[rt][q] = ov; pbk[rt][q] = ok;
                    }
                }
        }
        #pragma unroll
        for (int rt = 0; rt < 4; ++rt)
            #pragma unroll
            for (int q = 0; q < 4; ++q)
                if (li == rt * 4 + q) {
                    lvA[rt * 16 + lg * 4 + q][w] = pbv[rt][q];
                    lkA[rt * 16 + lg * 4 + q][w] = pbk[rt][q];
                }
        __syncthreads();

        // ---- phase A2+B: combine across 8 waves; margin counts ----
        float rbv[4][4]; int rbk[4][4]; int rcnt[4][4];
        #pragma unroll
        for (int rt = 0; rt < 4; ++rt)
            #pragma unroll
            for (int q = 0; q < 4; ++q) {
                int row = rt * 16 + lg * 4 + q;
                float bv = lvA[row][0]; int bk = lkA[row][0];
                #pragma unroll
                for (int ww = 1; ww < NW; ++ww) {
                    float v = lvA[row][ww]; int k = lkA[row][ww];
                    if (v < bv || (v == bv && k < bk)) { bv = v; bk = k; }
                }
                rbv[rt][q] = bv; rbk[rt][q] = bk;
                int c = 0;
                #pragma unroll
                for (int jc = 0; jc < 2; ++jc) {
                    float sv = ccl2[jc] - 2.0f * acc[rt][jc][q];
                    c += (sv <= bv + MARGIN) ? 1 : 0;
                }
                rcnt[rt][q] = c;
            }
        #pragma unroll
        for (int m = 1; m < 16; m <<= 1) {
            #pragma unroll
            for (int rt = 0; rt < 4; ++rt)
                #pragma unroll
                for (int q = 0; q < 4; ++q)
                    rcnt[rt][q] += __shfl_xor(rcnt[rt][q], m);
        }
        #pragma unroll
        for (int rt = 0; rt < 4; ++rt)
            #pragma unroll
            for (int q = 0; q < 4; ++q)
                if (li == rt * 4 + q) cntA[rt * 16 + lg * 4 + q][w] = rcnt[rt][q];
        __syncthreads();
        #pragma unroll
        for (int rt = 0; rt < 4; ++rt)
            #pragma unroll
            for (int q = 0; q < 4; ++q) {
                int row = rt * 16 + lg * 4 + q;
                int c = 0;
                #pragma unroll
                for (int ww = 0; ww < NW; ++ww) c += cntA[row][ww];
                rcnt[rt][q] = c;
                if (w == 0 && li == rt * 4 + q && c == 1)
                    codes_s[row][s] = rbk[rt][q] & 0xFF;
            }

        // ---- phase C: exact np-f32 refine for rows with >=2 margin candidates ----
        #pragma unroll
        for (int rt = 0; rt < 4; ++rt)
            #pragma unroll
            for (int q = 0; q < 4; ++q) {
                float bd = 3.4e38f; int bk = 1 << 30;
                if (rcnt[rt][q] >= 2) {
                    int row = rt * 16 + lg * 4 + q;
                    const float thr = rbv[rt][q] + MARGIN;
                    const float* rrow = &res[row][0];
                    #pragma unroll
                    for (int jc = 0; jc < 2; ++jc) {
                        float sv = ccl2[jc] - 2.0f * acc[rt][jc][q];
                        if (sv <= thr) {
                            int k = w * 32 + jc * 16 + li;
                            const float* crow = cbs + (size_t)k * DIM;
                            float a32 = 0.0f;
                            for (int d = 0; d < DIM; ++d)
                                a32 = fmaf(rrow[d], crow[d], a32);
                            float T  = rowA[row] + ccl2[jc];   // fl(A + B_k)
                            float dv = T - 2.0f * a32;         // fl(T - 2M), 2M exact
                            if (dv < bd || (dv == bd && k < bk)) { bd = dv; bk = k; }
                        }
                    }
                }
                pbv[rt][q] = bd; pbk[rt][q] = bk;
            }
        #pragma unroll
        for (int m = 1; m < 16; m <<= 1) {
            #pragma unroll
            for (int rt = 0; rt < 4; ++rt)
                #pragma unroll
                for (int q = 0; q < 4; ++q) {
                    float ov = __shfl_xor(pbv[rt][q], m);
                    int   ok = __shfl_xor(pbk[rt][q], m);
                    if (ov < pbv[rt][q] || (ov == pbv[rt][q] && ok < pbk[rt][q])) {
                        pbv[rt][q] = ov; pbk[rt][q] = ok;
                    }
                }
        }
        #pragma unroll
        for (int rt = 0; rt < 4; ++rt)
            #pragma unroll
            for (int q = 0; q < 4; ++q)
                if (li == rt * 4 + q) {
                    lvA[rt * 16 + lg * 4 + q][w] = pbv[rt][q];
                    lkA[rt * 16 + lg * 4 + q][w] = pbk[rt][q];
                }
        __syncthreads();
        #pragma unroll
        for (int rt = 0; rt < 4; ++rt)
            #pragma unroll
            for (int q = 0; q < 4; ++q)
                if (w == 0 && li == rt * 4 + q && rcnt[rt][q] >= 2) {
                    int row = rt * 16 + lg * 4 + q;
                    float bv = lvA[row][0]; int bk = lkA[row][0];
                    #pragma unroll
                    for (int ww = 1; ww < NW; ++ww) {
                        float v = lvA[row][ww]; int k = lkA[row][ww];
                        if (v < bv || (v == bv && k < bk)) { bv = v; bk = k; }
                    }
                    codes_s[row][s] = bk & 0xFF;
                }
        __syncthreads();          // codes_s ready for chain

        // ---- incremental chain: df = q - res; qst = res + df; rec += qst ----
        #pragma unroll
        for (int i = 0; i < 12; ++i) {
            int L = i * THREADS + t;
            int r = L / 96, c4 = L % 96;
            int code = codes_s[r][s] & 0xFF;
            float4 q  = ((const float4*)(cbs + (size_t)code * DIM))[c4];
            float4 rs = *(const float4*)&res[r][c4 * 4];
            float4 df;
            df.x = q.x - rs.x; df.y = q.y - rs.y;
            df.z = q.z - rs.z; df.w = q.w - rs.w;
            float4 qst;                       // fl(r + fl(q - r))
            qst.x = rs.x + df.x; qst.y = rs.y + df.y;
            qst.z = rs.z + df.z; qst.w = rs.w + df.w;
            rec[i].x = rec[i].x + qst.x; rec[i].y = rec[i].y + qst.y;
            rec[i].z = rec[i].z + qst.z; rec[i].w = rec[i].w + qst.w;
            lsum = fma((double)df.x, (double)df.x, lsum);
            lsum = fma((double)df.y, (double)df.y, lsum);
            lsum = fma((double)df.z, (double)df.z, lsum);
            lsum = fma((double)df.w, (double)df.w, lsum);
        }
    }

    // ---- reconstructed: write rec regs as f32 into out[0 .. B*D) ----
    #pragma unroll
    for (int i = 0; i < 12; ++i) {
        int L = i * THREADS + t;
        ((float4*)out)[(size_t)blockIdx.x * (ROWS * 96) + L] = rec[i];
    }

    // ---- codes as f32 values into out[B*D .. B*D + B*4) ----
    if (t < ROWS) {
        float4 c;
        c.x = (float)(codes_s[t][0] & 0xFF);
        c.y = (float)(codes_s[t][1] & 0xFF);
        c.z = (float)(codes_s[t][2] & 0xFF);
        c.w = (float)(codes_s[t][3] & 0xFF);
        *(float4*)&out[(size_t)BATCH * DIM + (size_t)(row0 + t) * NCB] = c;
    }

    // ---- per-block loss partial ----
    red[t] = lsum;
    __syncthreads();
    for (int st = 256; st > 0; st >>= 1) {
        if (t < st) red[t] += red[t + st];
        __syncthreads();
    }
    if (t == 0) loss_part[blockIdx.x] = red[0];
}

__global__ __launch_bounds__(256) void loss_fin(const double* __restrict__ loss_part,
                                                float* __restrict__ out) {
    __shared__ double red[256];
    int t = threadIdx.x;
    double s = 0.0;
    for (int i = t; i < BATCH / ROWS; i += 256) s += loss_part[i];
    red[t] = s;
    __syncthreads();
    for (int st = 128; st > 0; st >>= 1) {
        if (t < st) red[t] += red[t + st];
        __syncthreads();
    }
    if (t == 0) {
        double total = red[0] * (2.0 / ((double)BATCH * (double)DIM));
        out[(size_t)BATCH * DIM + (size_t)BATCH * NCB] = (float)total;
    }
}

extern "C" void kernel_launch(void* const* d_in, const int* in_sizes, int n_in,
                              void* d_out, int out_size, void* d_ws, size_t ws_size,
                              hipStream_t stream) {
    const float* x  = (const float*)d_in[0];
    const float* cb = (const float*)d_in[1];
    float* out = (float*)d_out;

    double* loss_part = (double*)d_ws;                        // 16 KB @ 0
    float*  bpw       = (float*)((char*)d_ws + 16384);        //  4 KB
    short*  cbh_g     = (short*)((char*)d_ws + 32768);        // 768 KB
    short*  cbl_g     = (short*)((char*)d_ws + 32768 + 786432);

    ccb_kernel<<<dim3(4), dim3(256), 0, stream>>>(cb, bpw);
    split_kernel<<<dim3((NCB * NKT * KC * 32 + 255) / 256), dim3(256), 0, stream>>>(cb, cbh_g, cbl_g);
    rq_main<<<dim3(BATCH / ROWS), dim3(THREADS), 0, stream>>>(x, cb, out, bpw,
                                                              cbh_g, cbl_g, loss_part);
    loss_fin<<<dim3(1), dim3(256), 0, stream>>>(loss_part, out);
}

// Round 8
// 1527.046 us; speedup vs baseline: 1.9135x; 1.1417x over previous
//
#include <hip/hip_runtime.h>
#include <hip/hip_bf16.h>

#define BATCH   131072
#define DIM     384
#define KC      256
#define NCB     4
#define ROWS    64
#define THREADS 512
#define RES_LD  388   // padded row stride (floats) for residual tile
#define NKT     12    // k-tiles of 32 (384 = 12*32)
#define NW      8     // waves per block
#define MARGIN  2.5e-4f

typedef __attribute__((ext_vector_type(8))) short bf16x8;
typedef __attribute__((ext_vector_type(4))) float f32x4;

// numpy pairwise_sum, n=96 block of squares, 8 accumulators (order-preserving).
__device__ __forceinline__ float pw96_sq(const float* a) {
#pragma clang fp contract(off)
    float r0 = a[0]*a[0], r1 = a[1]*a[1], r2 = a[2]*a[2], r3 = a[3]*a[3];
    float r4 = a[4]*a[4], r5 = a[5]*a[5], r6 = a[6]*a[6], r7 = a[7]*a[7];
    for (int i = 8; i < 96; i += 8) {
        r0 += a[i+0]*a[i+0]; r1 += a[i+1]*a[i+1];
        r2 += a[i+2]*a[i+2]; r3 += a[i+3]*a[i+3];
        r4 += a[i+4]*a[i+4]; r5 += a[i+5]*a[i+5];
        r6 += a[i+6]*a[i+6]; r7 += a[i+7]*a[i+7];
    }
    return ((r0+r1)+(r2+r3))+((r4+r5)+(r6+r7));
}

// B_k = numpy pairwise sum of cb_k^2 over 384: ((P0+P1)+(P2+P3))
__global__ __launch_bounds__(256) void ccb_kernel(const float* __restrict__ cb,
                                                  float* __restrict__ bpw) {
    int i = blockIdx.x * 256 + threadIdx.x;
    if (i >= NCB * KC) return;
    const float* row = cb + (size_t)i * DIM;
    {
#pragma clang fp contract(off)
        float P0 = pw96_sq(row), P1 = pw96_sq(row + 96);
        float P2 = pw96_sq(row + 192), P3 = pw96_sq(row + 288);
        bpw[i] = (P0 + P1) + (P2 + P3);
    }
}

// Split codebook into k-tile-major bf16 hi/lo: out[((s*NKT+kt)*KC+cand)*32 + k]
__global__ __launch_bounds__(256) void split_kernel(const float* __restrict__ cb,
                                                    short* __restrict__ hi,
                                                    short* __restrict__ lo) {
    int idx = blockIdx.x * 256 + threadIdx.x;   // over 4*12*256*32 = 393216 elems
    if (idx >= NCB * NKT * KC * 32) return;
    int k    = idx & 31;
    int cand = (idx >> 5) & 255;
    int kt   = (idx >> 13) % NKT;
    int s    = idx / (NKT * KC * 32);
    float v = cb[((size_t)(s * KC + cand)) * DIM + kt * 32 + k];
    __hip_bfloat16 h = __float2bfloat16(v);
    float hv = __bfloat162float(h);
    __hip_bfloat16 l = __float2bfloat16(v - hv);
    hi[idx] = *reinterpret_cast<short*>(&h);
    lo[idx] = *reinterpret_cast<short*>(&l);
}

__device__ __forceinline__ void cvt8(const float* p, bf16x8& hi, bf16x8& lo) {
    #pragma unroll
    for (int i = 0; i < 8; ++i) {
        float v = p[i];
        __hip_bfloat16 h = __float2bfloat16(v);
        float hv = __bfloat162float(h);
        __hip_bfloat16 l = __float2bfloat16(v - hv);
        hi[i] = *reinterpret_cast<short*>(&h);
        lo[i] = *reinterpret_cast<short*>(&l);
    }
}

__global__ __launch_bounds__(512, 1) void rq_main(const float* __restrict__ x,
                                                  const float* __restrict__ cb,
                                                  float* __restrict__ out,
                                                  const float* __restrict__ bpw,
                                                  const short* __restrict__ cbh_g,
                                                  const short* __restrict__ cbl_g,
                                                  double* __restrict__ loss_part) {
    __shared__ float  res[ROWS][RES_LD];      // 99328 B
    __shared__ float  rowP[ROWS][4];          //  1024 B
    __shared__ float  rowA[ROWS];             //   256 B
    __shared__ float  lvA[ROWS][NW];          //  2048 B
    __shared__ int    lkA[ROWS][NW];          //  2048 B
    __shared__ int    cntA[ROWS][NW];         //  2048 B
    __shared__ int    codes_s[ROWS][NCB];     //  1024 B
    __shared__ double red[THREADS];           //  4096 B   => 111872 B

    const int t  = threadIdx.x;
    const int w  = t >> 6;        // wave 0..7 (owns cand-tiles 2w, 2w+1)
    const int l  = t & 63;
    const int lg = l >> 4;        // k-group 0..3
    const int li = l & 15;
    const int row0 = blockIdx.x * ROWS;
    const float4* x4 = (const float4*)(x + (size_t)row0 * DIM);

    float4 rec[12];               // running reconstruction, this thread's 12 float4s
    #pragma unroll
    for (int i = 0; i < 12; ++i) rec[i] = make_float4(0.f, 0.f, 0.f, 0.f);

    double lsum = 0.0;

    for (int s = 0; s < NCB; ++s) {
        const float* cbs = cb + (size_t)s * KC * DIM;

        // ---- res_s = fl(x - rec) (bit-exact np; s=0: x-0 = x), write to LDS ----
        __syncthreads();          // prior stage's res readers (refine+chain) done
        #pragma unroll
        for (int i = 0; i < 12; ++i) {
            int L = i * THREADS + t;
            int r = L / 96, c4 = L % 96;
            float4 xv = x4[L];
            float4 rs;
            rs.x = xv.x - rec[i].x; rs.y = xv.y - rec[i].y;
            rs.z = xv.z - rec[i].z; rs.w = xv.w - rec[i].w;
            *(float4*)&res[r][c4 * 4] = rs;
        }
        __syncthreads();

        // ---- rowA = numpy-pairwise sum of res^2 (bit-exact np order) ----
        if (t < 256) {
            int r = t >> 2, qi = t & 3;
            rowP[r][qi] = pw96_sq(&res[r][qi * 96]);
        }
        __syncthreads();
        if (t < ROWS) {
#pragma clang fp contract(off)
            rowA[t] = (rowP[t][0] + rowP[t][1]) + (rowP[t][2] + rowP[t][3]);
        }
        // rowA consumed in refine; ordered by the phase-A barrier below

        // ---- MFMA screen: acc[rt][jc] = rows rt*16.. x cands (2w+jc)*16.. ----
        // B fragments straight from global (L2-resident), 2-deep pipelined;
        // kt loop is barrier-free (res is read-only during it).
        f32x4 acc[4][2];
        #pragma unroll
        for (int a = 0; a < 4; ++a)
            #pragma unroll
            for (int b = 0; b < 2; ++b) acc[a][b] = (f32x4){0.f, 0.f, 0.f, 0.f};

        const size_t sbase = (size_t)s * NKT * KC * 32;
        const int    coff  = (w * 32 + li) * 32 + lg * 8;   // +jc*512 per cand-tile

        bf16x8 bhv[2][2], blv[2][2];
        #pragma unroll
        for (int jc = 0; jc < 2; ++jc) {
            size_t off = sbase + (size_t)(coff + jc * 512);
            bhv[0][jc] = *(const bf16x8*)(cbh_g + off);
            blv[0][jc] = *(const bf16x8*)(cbl_g + off);
        }
        #pragma unroll
        for (int kt = 0; kt < NKT; ++kt) {
            const int cur = kt & 1, nxt = cur ^ 1;
            if (kt + 1 < NKT) {
                #pragma unroll
                for (int jc = 0; jc < 2; ++jc) {
                    size_t off = sbase + (size_t)(kt + 1) * (KC * 32)
                               + (size_t)(coff + jc * 512);
                    bhv[nxt][jc] = *(const bf16x8*)(cbh_g + off);
                    blv[nxt][jc] = *(const bf16x8*)(cbl_g + off);
                }
            }
            #pragma unroll
            for (int rt = 0; rt < 4; ++rt) {
                bf16x8 ah, al;
                cvt8(&res[rt * 16 + li][kt * 32 + lg * 8], ah, al);
                #pragma unroll
                for (int jc = 0; jc < 2; ++jc) {
                    acc[rt][jc] = __builtin_amdgcn_mfma_f32_16x16x32_bf16(ah, bhv[cur][jc], acc[rt][jc], 0, 0, 0);
                    acc[rt][jc] = __builtin_amdgcn_mfma_f32_16x16x32_bf16(ah, blv[cur][jc], acc[rt][jc], 0, 0, 0);
                    acc[rt][jc] = __builtin_amdgcn_mfma_f32_16x16x32_bf16(al, bhv[cur][jc], acc[rt][jc], 0, 0, 0);
                }
            }
        }

        // C/D frag: acc[rt][jc][q] = dot(row = rt*16 + lg*4 + q, cand = (2w+jc)*16 + li)
        float ccl2[2];
        #pragma unroll
        for (int jc = 0; jc < 2; ++jc) ccl2[jc] = bpw[s * KC + w * 32 + jc * 16 + li];

        // ---- phase A: per-lane best over jc; butterfly over li; to LDS per wave ----
        float pbv[4][4]; int pbk[4][4];
        #pragma unroll
        for (int rt = 0; rt < 4; ++rt)
            #pragma unroll
            for (int q = 0; q < 4; ++q) {
                float bv = 3.4e38f; int bk = 1 << 30;
                #pragma unroll
                for (int jc = 0; jc < 2; ++jc) {
                    float sv = ccl2[jc] - 2.0f * acc[rt][jc][q];
                    int k = w * 32 + jc * 16 + li;
                    if (sv < bv || (sv == bv && k < bk)) { bv = sv; bk = k; }
                }
                pbv[rt][q] = bv; pbk[rt][q] = bk;
            }
        #pragma unroll
        for (int m = 1; m < 16; m <<= 1) {
            #pragma unroll
            for (int rt = 0; rt < 4; ++rt)
                #pragma unroll
                for (int q = 0; q < 4; ++q) {
                    float ov = __shfl_xor(pbv[rt][q], m);
                    int   ok = __shfl_xor(pbk[rt][q], m);
                    if (ov < pbv[rt][q] || (ov == pbv[rt][q] && ok < pbk[rt][q])) {
                        pbv[rt][q] = ov; pbk[rt][q] = ok;
                    }
                }
        }
        #pragma unroll
        for (int rt = 0; rt < 4; ++rt)
            #pragma unroll
            for (int q = 0; q < 4; ++q)
                if (li == rt * 4 + q) {
                    lvA[rt * 16 + lg * 4 + q][w] = pbv[rt][q];
                    lkA[rt * 16 + lg * 4 + q][w] = pbk[rt][q];
                }
        __syncthreads();

        // ---- phase A2+B: combine across 8 waves; margin counts ----
        float rbv[4][4]; int rbk[4][4]; int rcnt[4][4];
        #pragma unroll
        for (int rt = 0; rt < 4; ++rt)
            #pragma unroll
            for (int q = 0; q < 4; ++q) {
                int row = rt * 16 + lg * 4 + q;
                float bv = lvA[row][0]; int bk = lkA[row][0];
                #pragma unroll
                for (int ww = 1; ww < NW; ++ww) {
                    float v = lvA[row][ww]; int k = lkA[row][ww];
                    if (v < bv || (v == bv && k < bk)) { bv = v; bk = k; }
                }
                rbv[rt][q] = bv; rbk[rt][q] = bk;
                int c = 0;
                #pragma unroll
                for (int jc = 0; jc < 2; ++jc) {
                    float sv = ccl2[jc] - 2.0f * acc[rt][jc][q];
                    c += (sv <= bv + MARGIN) ? 1 : 0;
                }
                rcnt[rt][q] = c;
            }
        #pragma unroll
        for (int m = 1; m < 16; m <<= 1) {
            #pragma unroll
            for (int rt = 0; rt < 4; ++rt)
                #pragma unroll
                for (int q = 0; q < 4; ++q)
                    rcnt[rt][q] += __shfl_xor(rcnt[rt][q], m);
        }
        #pragma unroll
        for (int rt = 0; rt < 4; ++rt)
            #pragma unroll
            for (int q = 0; q < 4; ++q)
                if (li == rt * 4 + q) cntA[rt * 16 + lg * 4 + q][w] = rcnt[rt][q];
        __syncthreads();
        #pragma unroll
        for (int rt = 0; rt < 4; ++rt)
            #pragma unroll
            for (int q = 0; q < 4; ++q) {
                int row = rt * 16 + lg * 4 + q;
                int c = 0;
                #pragma unroll
                for (int ww = 0; ww < NW; ++ww) c += cntA[row][ww];
                rcnt[rt][q] = c;
                if (w == 0 && li == rt * 4 + q && c == 1)
                    codes_s[row][s] = rbk[rt][q] & 0xFF;
            }

        // ---- phase C: exact np-f32 refine for rows with >=2 margin candidates ----
        #pragma unroll
        for (int rt = 0; rt < 4; ++rt)
            #pragma unroll
            for (int q = 0; q < 4; ++q) {
                float bd = 3.4e38f; int bk = 1 << 30;
                if (rcnt[rt][q] >= 2) {
                    int row = rt * 16 + lg * 4 + q;
                    const float thr = rbv[rt][q] + MARGIN;
                    const float* rrow = &res[row][0];
                    #pragma unroll
                    for (int jc = 0; jc < 2; ++jc) {
                        float sv = ccl2[jc] - 2.0f * acc[rt][jc][q];
                        if (sv <= thr) {
                            int k = w * 32 + jc * 16 + li;
                            const float* crow = cbs + (size_t)k * DIM;
                            float a32 = 0.0f;
                            for (int d = 0; d < DIM; ++d)
                                a32 = fmaf(rrow[d], crow[d], a32);
                            float T  = rowA[row] + ccl2[jc];   // fl(A + B_k)
                            float dv = T - 2.0f * a32;         // fl(T - 2M), 2M exact
                            if (dv < bd || (dv == bd && k < bk)) { bd = dv; bk = k; }
                        }
                    }
                }
                pbv[rt][q] = bd; pbk[rt][q] = bk;
            }
        #pragma unroll
        for (int m = 1; m < 16; m <<= 1) {
            #pragma unroll
            for (int rt = 0; rt < 4; ++rt)
                #pragma unroll
                for (int q = 0; q < 4; ++q) {
                    float ov = __shfl_xor(pbv[rt][q], m);
                    int   ok = __shfl_xor(pbk[rt][q], m);
                    if (ov < pbv[rt][q] || (ov == pbv[rt][q] && ok < pbk[rt][q])) {
                        pbv[rt][q] = ov; pbk[rt][q] = ok;
                    }
                }
        }
        #pragma unroll
        for (int rt = 0; rt < 4; ++rt)
            #pragma unroll
            for (int q = 0; q < 4; ++q)
                if (li == rt * 4 + q) {
                    lvA[rt * 16 + lg * 4 + q][w] = pbv[rt][q];
                    lkA[rt * 16 + lg * 4 + q][w] = pbk[rt][q];
                }
        __syncthreads();
        #pragma unroll
        for (int rt = 0; rt < 4; ++rt)
            #pragma unroll
            for (int q = 0; q < 4; ++q)
                if (w == 0 && li == rt * 4 + q && rcnt[rt][q] >= 2) {
                    int row = rt * 16 + lg * 4 + q;
                    float bv = lvA[row][0]; int bk = lkA[row][0];
                    #pragma unroll
                    for (int ww = 1; ww < NW; ++ww) {
                        float v = lvA[row][ww]; int k = lkA[row][ww];
                        if (v < bv || (v == bv && k < bk)) { bv = v; bk = k; }
                    }
                    codes_s[row][s] = bk & 0xFF;
                }
        __syncthreads();          // codes_s ready for chain

        // ---- incremental chain: df = q - res; qst = res + df; rec += qst ----
        #pragma unroll
        for (int i = 0; i < 12; ++i) {
            int L = i * THREADS + t;
            int r = L / 96, c4 = L % 96;
            int code = codes_s[r][s] & 0xFF;
            float4 q  = ((const float4*)(cbs + (size_t)code * DIM))[c4];
            float4 rs = *(const float4*)&res[r][c4 * 4];
            float4 df;
            df.x = q.x - rs.x; df.y = q.y - rs.y;
            df.z = q.z - rs.z; df.w = q.w - rs.w;
            float4 qst;                       // fl(r + fl(q - r))
            qst.x = rs.x + df.x; qst.y = rs.y + df.y;
            qst.z = rs.z + df.z; qst.w = rs.w + df.w;
            rec[i].x = rec[i].x + qst.x; rec[i].y = rec[i].y + qst.y;
            rec[i].z = rec[i].z + qst.z; rec[i].w = rec[i].w + qst.w;
            lsum = fma((double)df.x, (double)df.x, lsum);
            lsum = fma((double)df.y, (double)df.y, lsum);
            lsum = fma((double)df.z, (double)df.z, lsum);
            lsum = fma((double)df.w, (double)df.w, lsum);
        }
    }

    // ---- reconstructed: write rec regs as f32 into out[0 .. B*D) ----
    #pragma unroll
    for (int i = 0; i < 12; ++i) {
        int L = i * THREADS + t;
        ((float4*)out)[(size_t)blockIdx.x * (ROWS * 96) + L] = rec[i];
    }

    // ---- codes as f32 values into out[B*D .. B*D + B*4) ----
    if (t < ROWS) {
        float4 c;
        c.x = (float)(codes_s[t][0] & 0xFF);
        c.y = (float)(codes_s[t][1] & 0xFF);
        c.z = (float)(codes_s[t][2] & 0xFF);
        c.w = (float)(codes_s[t][3] & 0xFF);
        *(float4*)&out[(size_t)BATCH * DIM + (size_t)(row0 + t) * NCB] = c;
    }

    // ---- per-block loss partial ----
    red[t] = lsum;
    __syncthreads();
    for (int st = 256; st > 0; st >>= 1) {
        if (t < st) red[t] += red[t + st];
        __syncthreads();
    }
    if (t == 0) loss_part[blockIdx.x] = red[0];
}

__global__ __launch_bounds__(256) void loss_fin(const double* __restrict__ loss_part,
                                                float* __restrict__ out) {
    __shared__ double red[256];
    int t = threadIdx.x;
    double s = 0.0;
    for (int i = t; i < BATCH / ROWS; i += 256) s += loss_part[i];
    red[t] = s;
    __syncthreads();
    for (int st = 128; st > 0; st >>= 1) {
        if (t < st) red[t] += red[t + st];
        __syncthreads();
    }
    if (t == 0) {
        double total = red[0] * (2.0 / ((double)BATCH * (double)DIM));
        out[(size_t)BATCH * DIM + (size_t)BATCH * NCB] = (float)total;
    }
}

extern "C" void kernel_launch(void* const* d_in, const int* in_sizes, int n_in,
                              void* d_out, int out_size, void* d_ws, size_t ws_size,
                              hipStream_t stream) {
    const float* x  = (const float*)d_in[0];
    const float* cb = (const float*)d_in[1];
    float* out = (float*)d_out;

    double* loss_part = (double*)d_ws;                        // 16 KB @ 0
    float*  bpw       = (float*)((char*)d_ws + 16384);        //  4 KB
    short*  cbh_g     = (short*)((char*)d_ws + 32768);        // 768 KB
    short*  cbl_g     = (short*)((char*)d_ws + 32768 + 786432);

    ccb_kernel<<<dim3(4), dim3(256), 0, stream>>>(cb, bpw);
    split_kernel<<<dim3((NCB * NKT * KC * 32 + 255) / 256), dim3(256), 0, stream>>>(cb, cbh_g, cbl_g);
    rq_main<<<dim3(BATCH / ROWS), dim3(THREADS), 0, stream>>>(x, cb, out, bpw,
                                                              cbh_g, cbl_g, loss_part);
    loss_fin<<<dim3(1), dim3(256), 0, stream>>>(loss_part, out);
}

// Round 9
// 1079.114 us; speedup vs baseline: 2.7078x; 1.4151x over previous
//
#include <hip/hip_runtime.h>
#include <hip/hip_bf16.h>

#define BATCH   131072
#define DIM     384
#define KC      256
#define NCB     4
#define ROWS    64
#define THREADS 512
#define RES_LD  388   // padded row stride (floats) for residual tile
#define NKT     12    // k-tiles of 32 (384 = 12*32)
#define NW      8     // waves per block
#define MARGIN  2.5e-4f

typedef __attribute__((ext_vector_type(8))) short bf16x8;
typedef __attribute__((ext_vector_type(4))) float f32x4;

// numpy pairwise_sum, n=96 block of squares, 8 accumulators (order-preserving).
__device__ __forceinline__ float pw96_sq(const float* a) {
#pragma clang fp contract(off)
    float r0 = a[0]*a[0], r1 = a[1]*a[1], r2 = a[2]*a[2], r3 = a[3]*a[3];
    float r4 = a[4]*a[4], r5 = a[5]*a[5], r6 = a[6]*a[6], r7 = a[7]*a[7];
    for (int i = 8; i < 96; i += 8) {
        r0 += a[i+0]*a[i+0]; r1 += a[i+1]*a[i+1];
        r2 += a[i+2]*a[i+2]; r3 += a[i+3]*a[i+3];
        r4 += a[i+4]*a[i+4]; r5 += a[i+5]*a[i+5];
        r6 += a[i+6]*a[i+6]; r7 += a[i+7]*a[i+7];
    }
    return ((r0+r1)+(r2+r3))+((r4+r5)+(r6+r7));
}

// B_k = numpy pairwise sum of cb_k^2 over 384: ((P0+P1)+(P2+P3))
__global__ __launch_bounds__(256) void ccb_kernel(const float* __restrict__ cb,
                                                  float* __restrict__ bpw) {
    int i = blockIdx.x * 256 + threadIdx.x;
    if (i >= NCB * KC) return;
    const float* row = cb + (size_t)i * DIM;
    {
#pragma clang fp contract(off)
        float P0 = pw96_sq(row), P1 = pw96_sq(row + 96);
        float P2 = pw96_sq(row + 192), P3 = pw96_sq(row + 288);
        bpw[i] = (P0 + P1) + (P2 + P3);
    }
}

// Split codebook into k-tile-major bf16 hi/lo: out[((s*NKT+kt)*KC+cand)*32 + k]
__global__ __launch_bounds__(256) void split_kernel(const float* __restrict__ cb,
                                                    short* __restrict__ hi,
                                                    short* __restrict__ lo) {
    int idx = blockIdx.x * 256 + threadIdx.x;   // over 4*12*256*32 = 393216 elems
    if (idx >= NCB * NKT * KC * 32) return;
    int k    = idx & 31;
    int cand = (idx >> 5) & 255;
    int kt   = (idx >> 13) % NKT;
    int s    = idx / (NKT * KC * 32);
    float v = cb[((size_t)(s * KC + cand)) * DIM + kt * 32 + k];
    __hip_bfloat16 h = __float2bfloat16(v);
    float hv = __bfloat162float(h);
    __hip_bfloat16 l = __float2bfloat16(v - hv);
    hi[idx] = *reinterpret_cast<short*>(&h);
    lo[idx] = *reinterpret_cast<short*>(&l);
}

__device__ __forceinline__ void cvt8(const float* p, bf16x8& hi, bf16x8& lo) {
    #pragma unroll
    for (int i = 0; i < 8; ++i) {
        float v = p[i];
        __hip_bfloat16 h = __float2bfloat16(v);
        float hv = __bfloat162float(h);
        __hip_bfloat16 l = __float2bfloat16(v - hv);
        hi[i] = *reinterpret_cast<short*>(&h);
        lo[i] = *reinterpret_cast<short*>(&l);
    }
}

__global__ __launch_bounds__(512) void rq_main(const float* __restrict__ x,
                                               const float* __restrict__ cb,
                                               float* __restrict__ out,
                                               const float* __restrict__ bpw,
                                               const short* __restrict__ cbh_g,
                                               const short* __restrict__ cbl_g,
                                               double* __restrict__ loss_part) {
    __shared__ float  res[ROWS][RES_LD];      // 99328 B
    __shared__ float  rowP[ROWS][4];          //  1024 B
    __shared__ float  rowA[ROWS];             //   256 B
    __shared__ float  rowbv[ROWS];            //   256 B
    __shared__ int    rowbk[ROWS];            //   256 B
    __shared__ int    rowcnt[ROWS];           //   256 B
    __shared__ float  lvA[ROWS][NW];          //  2048 B
    __shared__ int    lkA[ROWS][NW];          //  2048 B
    __shared__ int    cntA[ROWS][NW];         //  2048 B
    __shared__ int    codes_s[ROWS][NCB];     //  1024 B
    __shared__ double red[THREADS];           //  4096 B   => 112640 B

    const int t  = threadIdx.x;
    const int w  = t >> 6;        // wave 0..7 (owns cand-tiles 2w, 2w+1)
    const int l  = t & 63;
    const int lg = l >> 4;        // k-group 0..3
    const int li = l & 15;
    const int row0 = blockIdx.x * ROWS;
    const float4* x4 = (const float4*)(x + (size_t)row0 * DIM);

    float4 rec[12];               // running reconstruction, this thread's 12 float4s
    #pragma unroll
    for (int i = 0; i < 12; ++i) rec[i] = make_float4(0.f, 0.f, 0.f, 0.f);

    double lsum = 0.0;

    for (int s = 0; s < NCB; ++s) {
        const float* cbs = cb + (size_t)s * KC * DIM;

        // ---- res_s = fl(x - rec) (bit-exact np; s=0: x-0 = x), write to LDS ----
        __syncthreads();          // prior stage's res readers (refine+chain) done
        #pragma unroll
        for (int i = 0; i < 12; ++i) {
            int L = i * THREADS + t;
            int r = L / 96, c4 = L % 96;
            float4 xv = x4[L];
            float4 rs;
            rs.x = xv.x - rec[i].x; rs.y = xv.y - rec[i].y;
            rs.z = xv.z - rec[i].z; rs.w = xv.w - rec[i].w;
            *(float4*)&res[r][c4 * 4] = rs;
        }
        __syncthreads();

        // ---- rowA = numpy-pairwise sum of res^2 (bit-exact np order) ----
        if (t < 256) {
            int r = t >> 2, qi = t & 3;
            rowP[r][qi] = pw96_sq(&res[r][qi * 96]);
        }
        __syncthreads();
        if (t < ROWS) {
#pragma clang fp contract(off)
            rowA[t] = (rowP[t][0] + rowP[t][1]) + (rowP[t][2] + rowP[t][3]);
        }
        // rowA consumed in refine; ordered by the phase-A barrier below

        // ---- MFMA screen: acc[rt][jc] = rows rt*16.. x cands (2w+jc)*16.. ----
        // B fragments straight from global (L2-resident), 2-deep pipelined;
        // kt loop is barrier-free (res is read-only during it).
        f32x4 acc[4][2];
        #pragma unroll
        for (int a = 0; a < 4; ++a)
            #pragma unroll
            for (int b = 0; b < 2; ++b) acc[a][b] = (f32x4){0.f, 0.f, 0.f, 0.f};

        const size_t sbase = (size_t)s * NKT * KC * 32;
        const int    coff  = (w * 32 + li) * 32 + lg * 8;   // +jc*512 per cand-tile

        bf16x8 bhv[2][2], blv[2][2];
        #pragma unroll
        for (int jc = 0; jc < 2; ++jc) {
            size_t off = sbase + (size_t)(coff + jc * 512);
            bhv[0][jc] = *(const bf16x8*)(cbh_g + off);
            blv[0][jc] = *(const bf16x8*)(cbl_g + off);
        }
        #pragma unroll
        for (int kt = 0; kt < NKT; ++kt) {
            const int cur = kt & 1, nxt = cur ^ 1;
            if (kt + 1 < NKT) {
                #pragma unroll
                for (int jc = 0; jc < 2; ++jc) {
                    size_t off = sbase + (size_t)(kt + 1) * (KC * 32)
                               + (size_t)(coff + jc * 512);
                    bhv[nxt][jc] = *(const bf16x8*)(cbh_g + off);
                    blv[nxt][jc] = *(const bf16x8*)(cbl_g + off);
                }
            }
            #pragma unroll
            for (int rt = 0; rt < 4; ++rt) {
                bf16x8 ah, al;
                cvt8(&res[rt * 16 + li][kt * 32 + lg * 8], ah, al);
                #pragma unroll
                for (int jc = 0; jc < 2; ++jc) {
                    acc[rt][jc] = __builtin_amdgcn_mfma_f32_16x16x32_bf16(ah, bhv[cur][jc], acc[rt][jc], 0, 0, 0);
                    acc[rt][jc] = __builtin_amdgcn_mfma_f32_16x16x32_bf16(ah, blv[cur][jc], acc[rt][jc], 0, 0, 0);
                    acc[rt][jc] = __builtin_amdgcn_mfma_f32_16x16x32_bf16(al, bhv[cur][jc], acc[rt][jc], 0, 0, 0);
                }
            }
        }

        // C/D frag: acc[rt][jc][q] = dot(row = rt*16 + lg*4 + q, cand = (2w+jc)*16 + li)
        float ccl2[2];
        #pragma unroll
        for (int jc = 0; jc < 2; ++jc) ccl2[jc] = bpw[s * KC + w * 32 + jc * 16 + li];

        // ---- phase A: per-lane best over jc; butterfly over li; to LDS per wave ----
        float pbv[4][4]; int pbk[4][4];
        #pragma unroll
        for (int rt = 0; rt < 4; ++rt)
            #pragma unroll
            for (int q = 0; q < 4; ++q) {
                float bv = 3.4e38f; int bk = 1 << 30;
                #pragma unroll
                for (int jc = 0; jc < 2; ++jc) {
                    float sv = ccl2[jc] - 2.0f * acc[rt][jc][q];
                    int k = w * 32 + jc * 16 + li;
                    if (sv < bv || (sv == bv && k < bk)) { bv = sv; bk = k; }
                }
                pbv[rt][q] = bv; pbk[rt][q] = bk;
            }
        #pragma unroll
        for (int m = 1; m < 16; m <<= 1) {
            #pragma unroll
            for (int rt = 0; rt < 4; ++rt)
                #pragma unroll
                for (int q = 0; q < 4; ++q) {
                    float ov = __shfl_xor(pbv[rt][q], m);
                    int   ok = __shfl_xor(pbk[rt][q], m);
                    if (ov < pbv[rt][q] || (ov == pbv[rt][q] && ok < pbk[rt][q])) {
                        pbv[rt][q] = ov; pbk[rt][q] = ok;
                    }
                }
        }
        #pragma unroll
        for (int rt = 0; rt < 4; ++rt)
            #pragma unroll
            for (int q = 0; q < 4; ++q)
                if (li == rt * 4 + q) {
                    lvA[rt * 16 + lg * 4 + q][w] = pbv[rt][q];
                    lkA[rt * 16 + lg * 4 + q][w] = pbk[rt][q];
                }
        __syncthreads();

        // ---- row combine across 8 waves (t<64 serial, np tie-break) ----
        if (t < ROWS) {
            float bv = lvA[t][0]; int bk = lkA[t][0];
            #pragma unroll
            for (int ww = 1; ww < NW; ++ww) {
                float v = lvA[t][ww]; int k = lkA[t][ww];
                if (v < bv || (v == bv && k < bk)) { bv = v; bk = k; }
            }
            rowbv[t] = bv; rowbk[t] = bk;
        }
        __syncthreads();

        // ---- margin counts (read rowbv broadcast), butterfly over li ----
        int pcnt[4][4];
        #pragma unroll
        for (int rt = 0; rt < 4; ++rt)
            #pragma unroll
            for (int q = 0; q < 4; ++q) {
                int row = rt * 16 + lg * 4 + q;
                float thr = rowbv[row] + MARGIN;
                int c = 0;
                #pragma unroll
                for (int jc = 0; jc < 2; ++jc) {
                    float sv = ccl2[jc] - 2.0f * acc[rt][jc][q];
                    c += (sv <= thr) ? 1 : 0;
                }
                pcnt[rt][q] = c;
            }
        #pragma unroll
        for (int m = 1; m < 16; m <<= 1) {
            #pragma unroll
            for (int rt = 0; rt < 4; ++rt)
                #pragma unroll
                for (int q = 0; q < 4; ++q)
                    pcnt[rt][q] += __shfl_xor(pcnt[rt][q], m);
        }
        #pragma unroll
        for (int rt = 0; rt < 4; ++rt)
            #pragma unroll
            for (int q = 0; q < 4; ++q)
                if (li == rt * 4 + q) cntA[rt * 16 + lg * 4 + q][w] = pcnt[rt][q];
        __syncthreads();
        if (t < ROWS) {
            int c = 0;
            #pragma unroll
            for (int ww = 0; ww < NW; ++ww) c += cntA[t][ww];
            rowcnt[t] = c;
            if (c == 1) codes_s[t][s] = rowbk[t] & 0xFF;
        }
        __syncthreads();

        // ---- phase C: exact np-f32 refine for rows with >=2 margin candidates ----
        #pragma unroll
        for (int rt = 0; rt < 4; ++rt)
            #pragma unroll
            for (int q = 0; q < 4; ++q) {
                float bd = 3.4e38f; int bk = 1 << 30;
                int row = rt * 16 + lg * 4 + q;
                if (rowcnt[row] >= 2) {
                    const float thr = rowbv[row] + MARGIN;
                    const float* rrow = &res[row][0];
                    #pragma unroll
                    for (int jc = 0; jc < 2; ++jc) {
                        float sv = ccl2[jc] - 2.0f * acc[rt][jc][q];
                        if (sv <= thr) {
                            int k = w * 32 + jc * 16 + li;
                            const float* crow = cbs + (size_t)k * DIM;
                            float a32 = 0.0f;
                            for (int d = 0; d < DIM; ++d)
                                a32 = fmaf(rrow[d], crow[d], a32);
                            float T  = rowA[row] + ccl2[jc];   // fl(A + B_k)
                            float dv = T - 2.0f * a32;         // fl(T - 2M), 2M exact
                            if (dv < bd || (dv == bd && k < bk)) { bd = dv; bk = k; }
                        }
                    }
                }
                pbv[rt][q] = bd; pbk[rt][q] = bk;
            }
        #pragma unroll
        for (int m = 1; m < 16; m <<= 1) {
            #pragma unroll
            for (int rt = 0; rt < 4; ++rt)
                #pragma unroll
                for (int q = 0; q < 4; ++q) {
                    float ov = __shfl_xor(pbv[rt][q], m);
                    int   ok = __shfl_xor(pbk[rt][q], m);
                    if (ov < pbv[rt][q] || (ov == pbv[rt][q] && ok < pbk[rt][q])) {
                        pbv[rt][q] = ov; pbk[rt][q] = ok;
                    }
                }
        }
        #pragma unroll
        for (int rt = 0; rt < 4; ++rt)
            #pragma unroll
            for (int q = 0; q < 4; ++q)
                if (li == rt * 4 + q) {
                    lvA[rt * 16 + lg * 4 + q][w] = pbv[rt][q];
                    lkA[rt * 16 + lg * 4 + q][w] = pbk[rt][q];
                }
        __syncthreads();
        if (t < ROWS && rowcnt[t] >= 2) {
            float bv = lvA[t][0]; int bk = lkA[t][0];
            #pragma unroll
            for (int ww = 1; ww < NW; ++ww) {
                float v = lvA[t][ww]; int k = lkA[t][ww];
                if (v < bv || (v == bv && k < bk)) { bv = v; bk = k; }
            }
            codes_s[t][s] = bk & 0xFF;
        }
        __syncthreads();          // codes_s ready for chain

        // ---- incremental chain: df = q - res; qst = res + df; rec += qst ----
        #pragma unroll
        for (int i = 0; i < 12; ++i) {
            int L = i * THREADS + t;
            int r = L / 96, c4 = L % 96;
            int code = codes_s[r][s] & 0xFF;
            float4 q  = ((const float4*)(cbs + (size_t)code * DIM))[c4];
            float4 rs = *(const float4*)&res[r][c4 * 4];
            float4 df;
            df.x = q.x - rs.x; df.y = q.y - rs.y;
            df.z = q.z - rs.z; df.w = q.w - rs.w;
            float4 qst;                       // fl(r + fl(q - r))
            qst.x = rs.x + df.x; qst.y = rs.y + df.y;
            qst.z = rs.z + df.z; qst.w = rs.w + df.w;
            rec[i].x = rec[i].x + qst.x; rec[i].y = rec[i].y + qst.y;
            rec[i].z = rec[i].z + qst.z; rec[i].w = rec[i].w + qst.w;
            lsum = fma((double)df.x, (double)df.x, lsum);
            lsum = fma((double)df.y, (double)df.y, lsum);
            lsum = fma((double)df.z, (double)df.z, lsum);
            lsum = fma((double)df.w, (double)df.w, lsum);
        }
    }

    // ---- reconstructed: write rec regs as f32 into out[0 .. B*D) ----
    #pragma unroll
    for (int i = 0; i < 12; ++i) {
        int L = i * THREADS + t;
        ((float4*)out)[(size_t)blockIdx.x * (ROWS * 96) + L] = rec[i];
    }

    // ---- codes as f32 values into out[B*D .. B*D + B*4) ----
    if (t < ROWS) {
        float4 c;
        c.x = (float)(codes_s[t][0] & 0xFF);
        c.y = (float)(codes_s[t][1] & 0xFF);
        c.z = (float)(codes_s[t][2] & 0xFF);
        c.w = (float)(codes_s[t][3] & 0xFF);
        *(float4*)&out[(size_t)BATCH * DIM + (size_t)(row0 + t) * NCB] = c;
    }

    // ---- per-block loss partial ----
    red[t] = lsum;
    __syncthreads();
    for (int st = 256; st > 0; st >>= 1) {
        if (t < st) red[t] += red[t + st];
        __syncthreads();
    }
    if (t == 0) loss_part[blockIdx.x] = red[0];
}

__global__ __launch_bounds__(256) void loss_fin(const double* __restrict__ loss_part,
                                                float* __restrict__ out) {
    __shared__ double red[256];
    int t = threadIdx.x;
    double s = 0.0;
    for (int i = t; i < BATCH / ROWS; i += 256) s += loss_part[i];
    red[t] = s;
    __syncthreads();
    for (int st = 128; st > 0; st >>= 1) {
        if (t < st) red[t] += red[t + st];
        __syncthreads();
    }
    if (t == 0) {
        double total = red[0] * (2.0 / ((double)BATCH * (double)DIM));
        out[(size_t)BATCH * DIM + (size_t)BATCH * NCB] = (float)total;
    }
}

extern "C" void kernel_launch(void* const* d_in, const int* in_sizes, int n_in,
                              void* d_out, int out_size, void* d_ws, size_t ws_size,
                              hipStream_t stream) {
    const float* x  = (const float*)d_in[0];
    const float* cb = (const float*)d_in[1];
    float* out = (float*)d_out;

    double* loss_part = (double*)d_ws;                        // 16 KB @ 0
    float*  bpw       = (float*)((char*)d_ws + 16384);        //  4 KB
    short*  cbh_g     = (short*)((char*)d_ws + 32768);        // 768 KB
    short*  cbl_g     = (short*)((char*)d_ws + 32768 + 786432);

    ccb_kernel<<<dim3(4), dim3(256), 0, stream>>>(cb, bpw);
    split_kernel<<<dim3((NCB * NKT * KC * 32 + 255) / 256), dim3(256), 0, stream>>>(cb, cbh_g, cbl_g);
    rq_main<<<dim3(BATCH / ROWS), dim3(THREADS), 0, stream>>>(x, cb, out, bpw,
                                                              cbh_g, cbl_g, loss_part);
    loss_fin<<<dim3(1), dim3(256), 0, stream>>>(loss_part, out);
}